// Round 7
// baseline (804.496 us; speedup 1.0000x reference)
//
#include <hip/hip_runtime.h>
#include <hip/hip_bf16.h>

// RecNN: u = relu(contents @ W_u^T + b_u);
// 10 levels emb = relu([emb_L | emb_R | u_j] @ W_h^T + b_h)   (K=1536, NO
// hoisted v-GEMM -- see below).
//
// Round-11: de-hoist v. Evidence across R4-R10: every GEMM dispatch runs at
// hbm_bytes / dur ~= 1.6 TB/s regardless of schedule (BK 32/64, depth 1/2,
// occupancy 21-36%, conflicts 0-8M). Duration is set by bytes, so the lever
// is byte elimination: folding v = u_j @ W_hu^T into the level GEMM as a
// third A-chunk (K 1024 -> 1536 vs full W_h, ldb=1536) deletes the v-GEMM
// kernel (134 MB ~ 85 us) while keeping per-level bytes identical (u_j read
// replaces v read; v write gone). FLOP +50% per level but MfmaUtil is ~10%
// -- compute is free. u_j accumulates in fp32 MFMA (more accurate than the
// old bf16 v round-trip). u stays live through all levels, so emb ping-pong
// no longer aliases u (uses the space v occupied).
//
// GEMM1 = R10 gemm1_k64 unchanged. Levels = R9/R10 3-slot counted-vmcnt
// pipeline, XOR granule swizzle, coalesced epilogue.

typedef unsigned short u16;
typedef __attribute__((ext_vector_type(8))) short bf16x8;
typedef __attribute__((ext_vector_type(4))) float f32x4;
typedef __attribute__((ext_vector_type(2))) float f32x2;

#define BK 32

__device__ __forceinline__ u16 f2b(float f) {
  union { float f; unsigned u; } c; c.f = f;
  unsigned u = c.u;
  return (u16)((u + 0x7fffu + ((u >> 16) & 1u)) >> 16);  // RNE
}

__device__ __forceinline__ float b2f(unsigned hi16) {
  union { float f; unsigned u; } c; c.u = hi16 << 16; return c.f;
}

__device__ __forceinline__ void glds16(const void* g, void* l) {
  __builtin_amdgcn_global_load_lds(
      (__attribute__((address_space(1))) void*)g,
      (__attribute__((address_space(3))) void*)l, 16, 0, 0);
}

template <int N>
__device__ __forceinline__ void wait_barrier() {
  asm volatile("s_waitcnt vmcnt(%0) lgkmcnt(0)" :: "n"(N) : "memory");
  __builtin_amdgcn_s_barrier();
  asm volatile("" ::: "memory");
}

// ---------------------------------------------------------------------------
// GEMM1: u = relu(contents[M][256] @ W_u^T + b_u), out bf16 [M][512].
// BK=64, 2-buffer, reg-staged fp32->bf16 A, glds B, coalesced epilogue.
// (unchanged from round 10)
// ---------------------------------------------------------------------------
__global__ __launch_bounds__(256, 2)
void gemm1_k64(const float* __restrict__ A,      // [M][256] fp32
               const u16* __restrict__ W,        // Wub bf16 [512][256]
               const float* __restrict__ bias,
               u16* __restrict__ out,            // [M][512] bf16
               int M, int nBlkM) {
  constexpr int KK = 256, BK64 = 64, NK = KK / BK64;   // 4 steps
  __shared__ __align__(16) char pool[65536];           // 2x16KB A + 2x16KB B
  auto lA = [&](int s) { return (u16*)(pool + s * 16384); };
  auto lB = [&](int s) { return (u16*)(pool + 32768 + s * 16384); };
  float* ep = (float*)pool;   // epilogue transpose alias (16.9 KB, after sync)

  const int tid  = threadIdx.x;
  const int lane = tid & 63;
  const int wv   = tid >> 6;
  const int wrow = wv >> 1, wcol = wv & 1;

  int mb, nb;
  {
    int b = blockIdx.x;
    if ((nBlkM & 7) == 0) {
      int xcd = b & 7;
      nb = (b >> 3) & 3;
      mb = ((b >> 5) << 3) | xcd;
    } else { nb = b & 3; mb = b >> 2; }
  }
  const int mBase = mb * 128;
  const int n0    = nb * 128;

  // A staging: thread covers rows r0s, r0s+64, cols q*16..+15 (2 granules).
  const int r0s = tid >> 2, q = tid & 3;
  const float *a0p, *a1p;
  {
    int m0 = min(mBase + r0s, M - 1);
    int m1 = min(mBase + r0s + 64, M - 1);
    a0p = A + (size_t)m0 * KK + q * 16;
    a1p = A + (size_t)m1 * KK + q * 16;
  }
  const int ph0 = (2 * q) ^ (r0s & 7);   // phys granule of logical 2q; ^1 for 2q+1

  // B staging via glds: per wave 4 issues of 1KB (8 rows x 8 granules).
  const int rB  = wv * 32 + (lane >> 3);               // +t*8
  const int swB = ((lane & 7) ^ ((lane >> 3) & 7)) * 8;  // preswizzled src col
  const u16* bpp = W + (size_t)(n0 + rB) * 256 + swB;
  const int dB = rB * 64 + (lane & 7) * 8;             // +t*512 (lane-linear)

  f32x4 acc[4][4] = {};
  const int fm = lane & 15, ql = lane >> 4;

  auto stageB = [&](int s, int k0) {
#pragma unroll
    for (int t = 0; t < 4; t++)
      glds16(bpp + (size_t)t * 8 * 256 + k0, lB(s) + dB + t * 512);
  };
  float4 rg[8];
  auto loadA = [&](int k0) {
    const float4* s0 = (const float4*)(a0p + k0);
    const float4* s1 = (const float4*)(a1p + k0);
    rg[0] = s0[0]; rg[1] = s0[1]; rg[2] = s0[2]; rg[3] = s0[3];
    rg[4] = s1[0]; rg[5] = s1[1]; rg[6] = s1[2]; rg[7] = s1[3];
  };
  auto cvtA = [&](int s) {
    u16* Ab = lA(s);
#pragma unroll
    for (int h = 0; h < 2; h++) {
      const int r = r0s + h * 64;
      float4 x = rg[h * 4 + 0], y = rg[h * 4 + 1];
      float4 z = rg[h * 4 + 2], w = rg[h * 4 + 3];
      union { __hip_bfloat162 hh[4]; bf16x8 v; } o1, o2;
      o1.hh[0] = __float22bfloat162_rn({x.x, x.y});
      o1.hh[1] = __float22bfloat162_rn({x.z, x.w});
      o1.hh[2] = __float22bfloat162_rn({y.x, y.y});
      o1.hh[3] = __float22bfloat162_rn({y.z, y.w});
      o2.hh[0] = __float22bfloat162_rn({z.x, z.y});
      o2.hh[1] = __float22bfloat162_rn({z.z, z.w});
      o2.hh[2] = __float22bfloat162_rn({w.x, w.y});
      o2.hh[3] = __float22bfloat162_rn({w.z, w.w});
      *(bf16x8*)&Ab[r * 64 + ph0 * 8]       = o1.v;   // logical granule 2q
      *(bf16x8*)&Ab[r * 64 + (ph0 ^ 1) * 8] = o2.v;   // logical granule 2q+1
    }
  };
  auto compute64 = [&](int s) {
    const u16* Ab = lA(s);
    const u16* Bb = lB(s);
    __builtin_amdgcn_s_setprio(1);
#pragma unroll
    for (int kk = 0; kk < 2; kk++) {
      bf16x8 av[4], bv[4];
#pragma unroll
      for (int i = 0; i < 4; i++) {
        const int ra = wrow * 64 + i * 16 + fm;
        const int rb = wcol * 64 + i * 16 + fm;
        const int pg = ((kk * 4 + ql) ^ (fm & 7)) * 8;
        av[i] = *(const bf16x8*)&Ab[ra * 64 + pg];
        bv[i] = *(const bf16x8*)&Bb[rb * 64 + pg];
      }
#pragma unroll
      for (int i = 0; i < 4; i++)
#pragma unroll
        for (int j = 0; j < 4; j++)
          acc[i][j] = __builtin_amdgcn_mfma_f32_16x16x32_bf16(av[i], bv[j], acc[i][j], 0, 0, 0);
    }
    __builtin_amdgcn_s_setprio(0);
  };

  // prologue
  loadA(0);
  stageB(0, 0);
  cvtA(0);
  for (int ks = 0; ks < NK; ks++) {
    const int cur = ks & 1, nxt = cur ^ 1;
    __syncthreads();
    const bool more = (ks + 1 < NK);
    if (more) {
      loadA((ks + 1) * BK64);          // regs in flight under the MFMA stage
      stageB(nxt, (ks + 1) * BK64);    // glds in flight until next barrier
    }
    compute64(cur);
    if (more) cvtA(nxt);
  }
  __syncthreads();                     // staging dead before ep aliases it

  // epilogue: per-wave transpose through LDS, full-line b128 stores
  const int r0  = (lane >> 4) * 4;
  const int err = lane >> 3;
  const int eg  = lane & 7;
  float* epw = ep + wv * 16 * 66;
#pragma unroll
  for (int i = 0; i < 4; i++) {
#pragma unroll
    for (int j = 0; j < 4; j++)
#pragma unroll
      for (int r = 0; r < 4; r++)
        epw[(r0 + r) * 66 + j * 16 + fm] = acc[i][j][r];
    asm volatile("s_waitcnt lgkmcnt(0)" ::: "memory");
    __builtin_amdgcn_sched_barrier(0);
#pragma unroll
    for (int s = 0; s < 2; s++) {
      const int rr  = err + s * 8;
      const int m   = mBase + wrow * 64 + i * 16 + rr;
      const int col = n0 + wcol * 64 + eg * 8;
      float p[8];
#pragma unroll
      for (int h = 0; h < 4; h++) {
        f32x2 t = *(const f32x2*)&epw[rr * 66 + eg * 8 + 2 * h];
        p[2 * h] = t[0]; p[2 * h + 1] = t[1];
      }
      if (m < M) {
        float4 b0v = *(const float4*)(bias + col);
        float4 b1v = *(const float4*)(bias + col + 4);
        float bb[8] = {b0v.x, b0v.y, b0v.z, b0v.w, b1v.x, b1v.y, b1v.z, b1v.w};
        union { u16 u[8]; bf16x8 v; } o;
#pragma unroll
        for (int c = 0; c < 8; c++) {
          float v = p[c] + bb[c];
          o.u[c] = f2b(v > 0.f ? v : 0.f);
        }
        *(bf16x8*)(out + (size_t)m * 512 + col) = o.v;
      }
    }
    __builtin_amdgcn_sched_barrier(0);
  }
}

// ---------------------------------------------------------------------------
// Level GEMM: emb = relu([emb[c.x] | emb[c.y] | u_j] @ W_h^T + b_h).
// A gathered, K = 1536 (three 512-col chunks). R9/R10 structure: 3-slot
// rotation, counted vmcnt(4), XOR granule swizzle, coalesced epilogue.
// ---------------------------------------------------------------------------
__global__ __launch_bounds__(256, 3)
void gemm_lvl(const u16* __restrict__ embPrev,
              const int2* __restrict__ idx,
              const u16* __restrict__ uLvl,   // [M][512] bf16 (u_j rows)
              const u16* __restrict__ W,      // W_h bf16 [512][1536]
              const float* __restrict__ bias,
              u16* __restrict__ out,          // [M][512] bf16
              int M, int nBlkM) {
  constexpr int K = 1536, ldb = 1536;
  __shared__ __align__(16) char pool[6 * 8192];
  auto lAb = [&](int s) { return (u16*)(pool + s * 8192); };
  auto lBp = [&](int s) { return (u16*)(pool + 3 * 8192 + s * 8192); };
  float* ep = (float*)pool;   // epilogue transpose alias (16.9 KB, after sync)

  const int tid  = threadIdx.x;
  const int lane = tid & 63;
  const int wv   = tid >> 6;
  const int wrow = wv >> 1, wcol = wv & 1;

  int mb, nb;
  {
    int b = blockIdx.x;
    if ((nBlkM & 7) == 0) {
      int xcd = b & 7;
      nb = (b >> 3) & 3;
      mb = ((b >> 5) << 3) | xcd;
    } else { nb = b & 3; mb = b >> 2; }
  }
  const int mBase = mb * 128;
  const int n0    = nb * 128;

  const int rowA0 = tid >> 2;
  const int colq  = ((tid & 3) ^ ((tid >> 3) & 3)) * 8;

  const u16 *aL0, *aR0, *aU0, *aL1, *aR1, *aU1;
  {
    int m0 = min(mBase + rowA0, M - 1);
    int m1 = min(mBase + rowA0 + 64, M - 1);
    int2 c0 = idx[m0], c1 = idx[m1];
    aL0 = embPrev + (size_t)c0.x * 512 + colq;
    aR0 = embPrev + (size_t)c0.y * 512 + colq;
    aU0 = uLvl + (size_t)m0 * 512 + colq;
    aL1 = embPrev + (size_t)c1.x * 512 + colq;
    aR1 = embPrev + (size_t)c1.y * 512 + colq;
    aU1 = uLvl + (size_t)m1 * 512 + colq;
  }
  const u16* bp0 = W + (size_t)(n0 + rowA0) * ldb + colq;
  const u16* bp1 = W + (size_t)(n0 + rowA0 + 64) * ldb + colq;

  f32x4 acc[4][4] = {};
  const int fm  = lane & 15;
  const int q   = lane >> 4;
  const int gs8 = (q ^ ((fm >> 1) & 3)) * 8;
  const int nk  = K / BK;                 // 48

  auto stage = [&](int s, int k0) {
    // chunk: 0 = emb_L, 1 = emb_R, 2 = u_j (k0 uniform; colq<32 elems
    // never crosses a 512 boundary)
    const int c  = k0 >> 9;
    const int kc = k0 & 511;
    const u16* g0 = (c == 0) ? aL0 : (c == 1) ? aR0 : aU0;
    const u16* g1 = (c == 0) ? aL1 : (c == 1) ? aR1 : aU1;
    glds16(g0 + kc, lAb(s) + tid * 8);
    glds16(g1 + kc, lAb(s) + (tid + 256) * 8);
    glds16(bp0 + k0, lBp(s) + tid * 8);
    glds16(bp1 + k0, lBp(s) + (tid + 256) * 8);
  };

  auto compute = [&](int s) {
    bf16x8 av[4], bv[4];
    const u16* Ab = lAb(s);
    const u16* Bb = lBp(s);
#pragma unroll
    for (int i = 0; i < 4; i++) {
      av[i] = *(const bf16x8*)&Ab[(wrow * 64 + i * 16 + fm) * BK + gs8];
      bv[i] = *(const bf16x8*)&Bb[(wcol * 64 + i * 16 + fm) * BK + gs8];
    }
    __builtin_amdgcn_s_setprio(1);
#pragma unroll
    for (int i = 0; i < 4; i++)
#pragma unroll
      for (int j = 0; j < 4; j++)
        acc[i][j] = __builtin_amdgcn_mfma_f32_16x16x32_bf16(av[i], bv[j], acc[i][j], 0, 0, 0);
    __builtin_amdgcn_s_setprio(0);
  };

  stage(0, 0);
  asm volatile("" ::: "memory");
  stage(1, BK);

  int sl = 0;
  for (int ks = 0; ks < nk - 2; ks++) {
    wait_barrier<4>();
    int s1 = sl + 1; if (s1 == 3) s1 = 0;
    int s2 = s1 + 1; if (s2 == 3) s2 = 0;
    stage(s2, (ks + 2) * BK);
    compute(sl);
    sl = s1;
  }
  {
    wait_barrier<4>();
    int s1 = sl + 1; if (s1 == 3) s1 = 0;
    compute(sl);
    sl = s1;
  }
  wait_barrier<0>();
  compute(sl);

  __syncthreads();

  const int r0  = (lane >> 4) * 4;
  const int err = lane >> 3;
  const int eg  = lane & 7;
  float* epw = ep + wv * 16 * 66;
#pragma unroll
  for (int i = 0; i < 4; i++) {
#pragma unroll
    for (int j = 0; j < 4; j++)
#pragma unroll
      for (int r = 0; r < 4; r++)
        epw[(r0 + r) * 66 + j * 16 + fm] = acc[i][j][r];
    asm volatile("s_waitcnt lgkmcnt(0)" ::: "memory");
    __builtin_amdgcn_sched_barrier(0);
#pragma unroll
    for (int s = 0; s < 2; s++) {
      const int rr  = err + s * 8;
      const int m   = mBase + wrow * 64 + i * 16 + rr;
      const int col = n0 + wcol * 64 + eg * 8;
      float p[8];
#pragma unroll
      for (int h = 0; h < 4; h++) {
        f32x2 t = *(const f32x2*)&epw[rr * 66 + eg * 8 + 2 * h];
        p[2 * h] = t[0]; p[2 * h + 1] = t[1];
      }
      if (m < M) {
        float4 b0v = *(const float4*)(bias + col);
        float4 b1v = *(const float4*)(bias + col + 4);
        float bb[8] = {b0v.x, b0v.y, b0v.z, b0v.w, b1v.x, b1v.y, b1v.z, b1v.w};
        union { u16 u[8]; bf16x8 v; } o;
#pragma unroll
        for (int c = 0; c < 8; c++) {
          float v = p[c] + bb[c];
          o.u[c] = f2b(v > 0.f ? v : 0.f);
        }
        *(bf16x8*)(out + (size_t)m * 512 + col) = o.v;
      }
    }
    __builtin_amdgcn_sched_barrier(0);
  }
}

// One launch: convert W_u (512x256) and W_h (512x1536) fp32 -> bf16.
__global__ void cvt_weights(const float* __restrict__ Wu,
                            const float* __restrict__ Wh,
                            u16* __restrict__ Wub, u16* __restrict__ Whb) {
  const int nWu = 512 * 256 / 8;
  const int nWh = 512 * 1536 / 8;
  int i = blockIdx.x * blockDim.x + threadIdx.x;
  const float* src; u16* dst; int c;
  if (i < nWu) { src = Wu; dst = Wub; c = i; }
  else if (i < nWu + nWh) { src = Wh; dst = Whb; c = i - nWu; }
  else return;
  const float4* s = (const float4*)(src + (size_t)c * 8);
  float4 a = s[0], b = s[1];
  union { u16 u[8]; bf16x8 v; } o;
  o.u[0] = f2b(a.x); o.u[1] = f2b(a.y); o.u[2] = f2b(a.z); o.u[3] = f2b(a.w);
  o.u[4] = f2b(b.x); o.u[5] = f2b(b.y); o.u[6] = f2b(b.z); o.u[7] = f2b(b.w);
  *(bf16x8*)(dst + (size_t)c * 8) = o.v;
}

__global__ void cvt_bf16_to_f32(const u16* __restrict__ src, float* __restrict__ dst, int n4) {
  int i = blockIdx.x * blockDim.x + threadIdx.x;
  if (i >= n4) return;
  uint2 p = ((const uint2*)src)[i];
  float4 o;
  o.x = b2f(p.x & 0xffffu); o.y = b2f(p.x >> 16);
  o.z = b2f(p.y & 0xffffu); o.w = b2f(p.y >> 16);
  ((float4*)dst)[i] = o;
}

extern "C" void kernel_launch(void* const* d_in, const int* in_sizes, int n_in,
                              void* d_out, int out_size, void* d_ws, size_t ws_size,
                              hipStream_t stream) {
  const float* contents = (const float*)d_in[0];
  const int2*  children = (const int2*)d_in[1];
  const float* W_u = (const float*)d_in[2];
  const float* b_u = (const float*)d_in[3];
  const float* W_h = (const float*)d_in[4];
  const float* b_h = (const float*)d_in[5];
  float* out = (float*)d_out;

  const int B = 64, D = 11, F = 256, H = 512;
  const int N = B * ((1 << D) - 1);            // 131008
  const int NI = B * ((1 << (D - 1)) - 1);     // 65472

  // Workspace (u16 elems): u_bf [N*512] | embA [32768*512] | embB
  // [16384*512] | Wub | Whb.  u stays live through ALL levels (u_j is read
  // by every level) so emb ping-pong must NOT alias u.
  u16* ws16 = (u16*)d_ws;
  u16* u_bf = ws16;
  u16* embA = u_bf + (size_t)N * H;
  u16* embB = embA + (size_t)32768 * H;
  u16* Wub  = embB + (size_t)16384 * H;
  u16* Whb  = Wub + 512 * 256;

  // --- weight conversion (single tiny launch) ---
  {
    int n = (512 * 256 + 512 * 1536) / 8;
    cvt_weights<<<(n + 255) / 256, 256, 0, stream>>>(W_u, W_h, Wub, Whb);
  }

  // --- GEMM1: u = relu(contents @ W_u^T + b_u) ---
  {
    int mb = (N + 127) / 128;                  // 1024
    gemm1_k64<<<mb * 4, 256, 0, stream>>>(contents, Wub, b_u, u_bf, N, mb);
  }

  // --- tree levels j = D-2 .. 0: K=1536 gather [emb_L|emb_R|u_j] ---
  const u16* embPrev = u_bf + (size_t)NI * H;  // leaves = u[NI:]
  u16* dst = embA;
  for (int j = D - 2; j >= 0; --j) {
    int M = B << j;
    int o = B * ((1 << j) - 1);
    int mb = (M + 127) / 128;
    gemm_lvl<<<mb * 4, 256, 0, stream>>>(embPrev, children + o,
                                         u_bf + (size_t)o * H,
                                         Whb, b_h, dst, M, mb);
    embPrev = dst;
    dst = (dst == embA) ? embB : embA;
  }

  // --- level-0 emb (64 x 512) -> fp32 output ---
  {
    int n4 = B * H / 4;
    cvt_bf16_to_f32<<<(n4 + 255) / 256, 256, 0, stream>>>(embPrev, out, n4);
  }
}

// Round 8
// 548.424 us; speedup vs baseline: 1.4669x; 1.4669x over previous
//
#include <hip/hip_runtime.h>
#include <hip/hip_bf16.h>

// RecNN: u = relu(contents @ W_u^T + b_u); v = u[internal] @ W_hu^T (hoisted);
// 10 levels emb = relu([emb_L|emb_R] @ W_LR^T + v + b_h).
//
// Round-12 = R10 (best: 520 us) with levels/v-GEMM widened to 128x256 tiles
// (512 threads, 8 waves 2x4 of 64x64). Rationale: per-CU staging-request
// accounting matches the observed step time (MfmaUtil ~14% <=> ~1700cy/step
// <=> ~768 half-line requests/CU/step at ~1 req/cy TA) -- the wall is
// address/request throughput times the x4 A-panel re-read. 256-wide n-tiles
// halve A-gather requests and raise waves/CU 12->16. Schedule unchanged:
// 3-slot LDS rotation, counted vmcnt(3), stage-after-barrier, XOR granule
// swizzle (validated conflict-free), coalesced epilogue. GEMM1 = proven R10
// gemm1_k64 (BK=64, reg-staged fp32->bf16). De-hoist of v (R11) REVERTED:
// it regressed 520->804 (levels fell to ~1.1 TB/s with +16 exposed steps).

typedef unsigned short u16;
typedef __attribute__((ext_vector_type(8))) short bf16x8;
typedef __attribute__((ext_vector_type(4))) float f32x4;
typedef __attribute__((ext_vector_type(2))) float f32x2;

#define BK 32

__device__ __forceinline__ u16 f2b(float f) {
  union { float f; unsigned u; } c; c.f = f;
  unsigned u = c.u;
  return (u16)((u + 0x7fffu + ((u >> 16) & 1u)) >> 16);  // RNE
}

__device__ __forceinline__ float b2f(unsigned hi16) {
  union { float f; unsigned u; } c; c.u = hi16 << 16; return c.f;
}

__device__ __forceinline__ void glds16(const void* g, void* l) {
  __builtin_amdgcn_global_load_lds(
      (__attribute__((address_space(1))) void*)g,
      (__attribute__((address_space(3))) void*)l, 16, 0, 0);
}

template <int N>
__device__ __forceinline__ void wait_barrier() {
  asm volatile("s_waitcnt vmcnt(%0) lgkmcnt(0)" :: "n"(N) : "memory");
  __builtin_amdgcn_s_barrier();
  asm volatile("" ::: "memory");
}

// ---------------------------------------------------------------------------
// GEMM1: u = relu(contents[M][256] @ W_u^T + b_u), out bf16 [M][512].
// BK=64, 2-buffer, reg-staged fp32->bf16 A, glds B, coalesced epilogue.
// (unchanged from round 10: 129 us proven)
// ---------------------------------------------------------------------------
__global__ __launch_bounds__(256, 2)
void gemm1_k64(const float* __restrict__ A,      // [M][256] fp32
               const u16* __restrict__ W,        // Wub bf16 [512][256]
               const float* __restrict__ bias,
               u16* __restrict__ out,            // [M][512] bf16
               int M, int nBlkM) {
  constexpr int KK = 256, BK64 = 64, NK = KK / BK64;   // 4 steps
  __shared__ __align__(16) char pool[65536];           // 2x16KB A + 2x16KB B
  auto lA = [&](int s) { return (u16*)(pool + s * 16384); };
  auto lB = [&](int s) { return (u16*)(pool + 32768 + s * 16384); };
  float* ep = (float*)pool;   // epilogue transpose alias (16.9 KB, after sync)

  const int tid  = threadIdx.x;
  const int lane = tid & 63;
  const int wv   = tid >> 6;
  const int wrow = wv >> 1, wcol = wv & 1;

  int mb, nb;
  {
    int b = blockIdx.x;
    if ((nBlkM & 7) == 0) {
      int xcd = b & 7;
      nb = (b >> 3) & 3;
      mb = ((b >> 5) << 3) | xcd;
    } else { nb = b & 3; mb = b >> 2; }
  }
  const int mBase = mb * 128;
  const int n0    = nb * 128;

  // A staging: thread covers rows r0s, r0s+64, cols q*16..+15 (2 granules).
  const int r0s = tid >> 2, q = tid & 3;
  const float *a0p, *a1p;
  {
    int m0 = min(mBase + r0s, M - 1);
    int m1 = min(mBase + r0s + 64, M - 1);
    a0p = A + (size_t)m0 * KK + q * 16;
    a1p = A + (size_t)m1 * KK + q * 16;
  }
  const int ph0 = (2 * q) ^ (r0s & 7);   // phys granule of logical 2q; ^1 for 2q+1

  // B staging via glds: per wave 4 issues of 1KB (8 rows x 8 granules).
  const int rB  = wv * 32 + (lane >> 3);               // +t*8
  const int swB = ((lane & 7) ^ ((lane >> 3) & 7)) * 8;  // preswizzled src col
  const u16* bpp = W + (size_t)(n0 + rB) * 256 + swB;
  const int dB = rB * 64 + (lane & 7) * 8;             // +t*512 (lane-linear)

  f32x4 acc[4][4] = {};
  const int fm = lane & 15, ql = lane >> 4;

  auto stageB = [&](int s, int k0) {
#pragma unroll
    for (int t = 0; t < 4; t++)
      glds16(bpp + (size_t)t * 8 * 256 + k0, lB(s) + dB + t * 512);
  };
  float4 rg[8];
  auto loadA = [&](int k0) {
    const float4* s0 = (const float4*)(a0p + k0);
    const float4* s1 = (const float4*)(a1p + k0);
    rg[0] = s0[0]; rg[1] = s0[1]; rg[2] = s0[2]; rg[3] = s0[3];
    rg[4] = s1[0]; rg[5] = s1[1]; rg[6] = s1[2]; rg[7] = s1[3];
  };
  auto cvtA = [&](int s) {
    u16* Ab = lA(s);
#pragma unroll
    for (int h = 0; h < 2; h++) {
      const int r = r0s + h * 64;
      float4 x = rg[h * 4 + 0], y = rg[h * 4 + 1];
      float4 z = rg[h * 4 + 2], w = rg[h * 4 + 3];
      union { __hip_bfloat162 hh[4]; bf16x8 v; } o1, o2;
      o1.hh[0] = __float22bfloat162_rn({x.x, x.y});
      o1.hh[1] = __float22bfloat162_rn({x.z, x.w});
      o1.hh[2] = __float22bfloat162_rn({y.x, y.y});
      o1.hh[3] = __float22bfloat162_rn({y.z, y.w});
      o2.hh[0] = __float22bfloat162_rn({z.x, z.y});
      o2.hh[1] = __float22bfloat162_rn({z.z, z.w});
      o2.hh[2] = __float22bfloat162_rn({w.x, w.y});
      o2.hh[3] = __float22bfloat162_rn({w.z, w.w});
      *(bf16x8*)&Ab[r * 64 + ph0 * 8]       = o1.v;   // logical granule 2q
      *(bf16x8*)&Ab[r * 64 + (ph0 ^ 1) * 8] = o2.v;   // logical granule 2q+1
    }
  };
  auto compute64 = [&](int s) {
    const u16* Ab = lA(s);
    const u16* Bb = lB(s);
    __builtin_amdgcn_s_setprio(1);
#pragma unroll
    for (int kk = 0; kk < 2; kk++) {
      bf16x8 av[4], bv[4];
#pragma unroll
      for (int i = 0; i < 4; i++) {
        const int ra = wrow * 64 + i * 16 + fm;
        const int rb = wcol * 64 + i * 16 + fm;
        const int pg = ((kk * 4 + ql) ^ (fm & 7)) * 8;
        av[i] = *(const bf16x8*)&Ab[ra * 64 + pg];
        bv[i] = *(const bf16x8*)&Bb[rb * 64 + pg];
      }
#pragma unroll
      for (int i = 0; i < 4; i++)
#pragma unroll
        for (int j = 0; j < 4; j++)
          acc[i][j] = __builtin_amdgcn_mfma_f32_16x16x32_bf16(av[i], bv[j], acc[i][j], 0, 0, 0);
    }
    __builtin_amdgcn_s_setprio(0);
  };

  // prologue
  loadA(0);
  stageB(0, 0);
  cvtA(0);
  for (int ks = 0; ks < NK; ks++) {
    const int cur = ks & 1, nxt = cur ^ 1;
    __syncthreads();
    const bool more = (ks + 1 < NK);
    if (more) {
      loadA((ks + 1) * BK64);          // regs in flight under the MFMA stage
      stageB(nxt, (ks + 1) * BK64);    // glds in flight until next barrier
    }
    compute64(cur);
    if (more) cvtA(nxt);
  }
  __syncthreads();                     // staging dead before ep aliases it

  // epilogue: per-wave transpose through LDS, full-line b128 stores
  const int r0  = (lane >> 4) * 4;
  const int err = lane >> 3;
  const int eg  = lane & 7;
  float* epw = ep + wv * 16 * 66;
#pragma unroll
  for (int i = 0; i < 4; i++) {
#pragma unroll
    for (int j = 0; j < 4; j++)
#pragma unroll
      for (int r = 0; r < 4; r++)
        epw[(r0 + r) * 66 + j * 16 + fm] = acc[i][j][r];
    asm volatile("s_waitcnt lgkmcnt(0)" ::: "memory");
    __builtin_amdgcn_sched_barrier(0);
#pragma unroll
    for (int s = 0; s < 2; s++) {
      const int rr  = err + s * 8;
      const int m   = mBase + wrow * 64 + i * 16 + rr;
      const int col = n0 + wcol * 64 + eg * 8;
      float p[8];
#pragma unroll
      for (int h = 0; h < 4; h++) {
        f32x2 t = *(const f32x2*)&epw[rr * 66 + eg * 8 + 2 * h];
        p[2 * h] = t[0]; p[2 * h + 1] = t[1];
      }
      if (m < M) {
        float4 b0v = *(const float4*)(bias + col);
        float4 b1v = *(const float4*)(bias + col + 4);
        float bb[8] = {b0v.x, b0v.y, b0v.z, b0v.w, b1v.x, b1v.y, b1v.z, b1v.w};
        union { u16 u[8]; bf16x8 v; } o;
#pragma unroll
        for (int c = 0; c < 8; c++) {
          float v = p[c] + bb[c];
          o.u[c] = f2b(v > 0.f ? v : 0.f);
        }
        *(bf16x8*)(out + (size_t)m * 512 + col) = o.v;
      }
    }
    __builtin_amdgcn_sched_barrier(0);
  }
}

// ---------------------------------------------------------------------------
// Wide-tile GEMM: 128m x 256n, 512 threads (8 waves 2x4 of 64x64), BK=32,
// 3-slot counted-vmcnt pipeline (PEND=3: A=1 + B=2 glds/thread).
// MODE 2: A bf16 [M][K], raw store                               (v-GEMM)
// MODE 1: A gathered [emb[c.x] | emb[c.y]] (K=1024), +v+bias+relu (levels)
// ---------------------------------------------------------------------------
template <int MODE>
__global__ __launch_bounds__(512, 2)
void gemm_db(const u16* __restrict__ Abf,
             const u16* __restrict__ embPrev,
             const int2* __restrict__ idx,
             const u16* __restrict__ vLvl,   // [M][512] bf16
             const u16* __restrict__ W,      // bf16, row stride ldb (B^T)
             int ldb,
             const float* __restrict__ bias,
             u16* __restrict__ out,          // [M][512] bf16
             int M, int K, int nBlkM) {
  // per slot: A 128x32 bf16 = 8 KB, B 256x32 bf16 = 16 KB. 3 slots = 72 KB.
  __shared__ __align__(16) char pool[3 * 8192 + 3 * 16384];
  auto lAb = [&](int s) { return (u16*)(pool + s * 8192); };
  auto lBp = [&](int s) { return (u16*)(pool + 24576 + s * 16384); };
  float* ep = (float*)pool;   // epilogue alias: 8 waves x 4.2 KB = 33.8 KB

  const int tid  = threadIdx.x;
  const int lane = tid & 63;
  const int wv   = tid >> 6;                 // 0..7
  const int wrow = wv >> 2, wcol = wv & 3;   // 2 x 4 wave grid

  // XCD swizzle: the 2 n-blocks of one m-block -> same XCD (b%8).
  int mb, nb;
  {
    int b = blockIdx.x;
    if ((nBlkM & 7) == 0) {
      int xcd = b & 7;
      nb = (b >> 3) & 1;
      mb = ((b >> 4) << 3) | xcd;
    } else { nb = b & 1; mb = b >> 1; }
  }
  const int mBase = mb * 128;
  const int n0    = nb * 256;

  // A: 512 granules (128 rows x 4), one glds/thread, dest lane-linear.
  const int rowA = tid >> 2;
  const int colq = ((tid & 3) ^ ((tid >> 3) & 3)) * 8;   // preswizzled source

  const u16 *ab0 = nullptr, *aL0 = nullptr, *aR0 = nullptr;
  {
    int m0 = min(mBase + rowA, M - 1);
    if (MODE == 2) {
      ab0 = Abf + (size_t)m0 * K + colq;
    } else {
      int2 c0 = idx[m0];
      aL0 = embPrev + (size_t)c0.x * 512 + colq;
      aR0 = embPrev + (size_t)c0.y * 512 + colq;
    }
  }
  // B: 1024 granules (256 rows x 4), two glds/thread.
  // (rowA+128 has the same (row>>1)&3 as rowA, so colq applies to both.)
  const u16* bp0 = W + (size_t)(n0 + rowA) * ldb + colq;         // rows 0..127
  const u16* bp1 = W + (size_t)(n0 + rowA + 128) * ldb + colq;   // rows 128..255

  f32x4 acc[4][4] = {};
  const int fm  = lane & 15;
  const int gs8 = ((lane >> 4) ^ ((fm >> 1) & 3)) * 8;   // read-side XOR
  const int nk  = K / BK;

  auto stage = [&](int s, int k0) {       // exactly 3 glds per thread
    if (MODE == 2) {
      glds16(ab0 + k0, lAb(s) + tid * 8);
    } else {  // gather; colq < 32 elems never flips the L/R bit
      const u16* g0 = ((k0 & 512) ? aR0 : aL0) + (k0 & 511);
      glds16(g0, lAb(s) + tid * 8);
    }
    glds16(bp0 + k0, lBp(s) + tid * 8);
    glds16(bp1 + k0, lBp(s) + (tid + 512) * 8);
  };

  auto compute = [&](int s) {
    bf16x8 av[4], bv[4];
    const u16* Ab = lAb(s);
    const u16* Bb = lBp(s);
#pragma unroll
    for (int i = 0; i < 4; i++) {
      av[i] = *(const bf16x8*)&Ab[(wrow * 64 + i * 16 + fm) * BK + gs8];
      bv[i] = *(const bf16x8*)&Bb[(wcol * 64 + i * 16 + fm) * BK + gs8];
    }
    __builtin_amdgcn_s_setprio(1);
#pragma unroll
    for (int i = 0; i < 4; i++)
#pragma unroll
      for (int j = 0; j < 4; j++)
        acc[i][j] = __builtin_amdgcn_mfma_f32_16x16x32_bf16(av[i], bv[j], acc[i][j], 0, 0, 0);
    __builtin_amdgcn_s_setprio(0);
  };

  stage(0, 0);
  asm volatile("" ::: "memory");      // vmem group boundary
  stage(1, BK);

  int sl = 0;
  for (int ks = 0; ks < nk - 2; ks++) {
    wait_barrier<3>();                // slot ks ready; slot ks+1 in flight
    int s1 = sl + 1; if (s1 == 3) s1 = 0;
    int s2 = s1 + 1; if (s2 == 3) s2 = 0;
    stage(s2, (ks + 2) * BK);
    compute(sl);
    sl = s1;
  }
  {
    wait_barrier<3>();
    int s1 = sl + 1; if (s1 == 3) s1 = 0;
    compute(sl);
    sl = s1;
  }
  wait_barrier<0>();
  compute(sl);

  __syncthreads();                    // staging dead before ep aliases it

  // epilogue: per-wave transpose through LDS, full-line b128 stores
  const int r0  = (lane >> 4) * 4;
  const int err = lane >> 3;
  const int eg  = lane & 7;
  float* epw = ep + wv * 16 * 66;
#pragma unroll
  for (int i = 0; i < 4; i++) {
#pragma unroll
    for (int j = 0; j < 4; j++)
#pragma unroll
      for (int r = 0; r < 4; r++)
        epw[(r0 + r) * 66 + j * 16 + fm] = acc[i][j][r];
    asm volatile("s_waitcnt lgkmcnt(0)" ::: "memory");
    __builtin_amdgcn_sched_barrier(0);
#pragma unroll
    for (int s = 0; s < 2; s++) {
      const int rr  = err + s * 8;
      const int m   = mBase + wrow * 64 + i * 16 + rr;
      const int col = n0 + wcol * 64 + eg * 8;
      float p[8];
#pragma unroll
      for (int h = 0; h < 4; h++) {
        f32x2 t = *(const f32x2*)&epw[rr * 66 + eg * 8 + 2 * h];
        p[2 * h] = t[0]; p[2 * h + 1] = t[1];
      }
      if (m < M) {
        float bb[8];
        if (MODE != 2) {
          float4 b0v = *(const float4*)(bias + col);
          float4 b1v = *(const float4*)(bias + col + 4);
          bb[0] = b0v.x; bb[1] = b0v.y; bb[2] = b0v.z; bb[3] = b0v.w;
          bb[4] = b1v.x; bb[5] = b1v.y; bb[6] = b1v.z; bb[7] = b1v.w;
        }
        union { u16 u[8]; bf16x8 v; } vl;
        if (MODE == 1) vl.v = *(const bf16x8*)(vLvl + (size_t)m * 512 + col);
        union { u16 u[8]; bf16x8 v; } o;
#pragma unroll
        for (int c = 0; c < 8; c++) {
          float v = p[c];
          if (MODE != 2) v += bb[c];
          if (MODE == 1) v += b2f(vl.u[c]);
          if (MODE != 2) v = v > 0.f ? v : 0.f;
          o.u[c] = f2b(v);
        }
        *(bf16x8*)(out + (size_t)m * 512 + col) = o.v;
      }
    }
    __builtin_amdgcn_sched_barrier(0);
  }
}

// One launch: convert W_u (512x256) and W_h (512x1536) fp32 -> bf16.
__global__ void cvt_weights(const float* __restrict__ Wu,
                            const float* __restrict__ Wh,
                            u16* __restrict__ Wub, u16* __restrict__ Whb) {
  const int nWu = 512 * 256 / 8;
  const int nWh = 512 * 1536 / 8;
  int i = blockIdx.x * blockDim.x + threadIdx.x;
  const float* src; u16* dst; int c;
  if (i < nWu) { src = Wu; dst = Wub; c = i; }
  else if (i < nWu + nWh) { src = Wh; dst = Whb; c = i - nWu; }
  else return;
  const float4* s = (const float4*)(src + (size_t)c * 8);
  float4 a = s[0], b = s[1];
  union { u16 u[8]; bf16x8 v; } o;
  o.u[0] = f2b(a.x); o.u[1] = f2b(a.y); o.u[2] = f2b(a.z); o.u[3] = f2b(a.w);
  o.u[4] = f2b(b.x); o.u[5] = f2b(b.y); o.u[6] = f2b(b.z); o.u[7] = f2b(b.w);
  *(bf16x8*)(dst + (size_t)c * 8) = o.v;
}

__global__ void cvt_bf16_to_f32(const u16* __restrict__ src, float* __restrict__ dst, int n4) {
  int i = blockIdx.x * blockDim.x + threadIdx.x;
  if (i >= n4) return;
  uint2 p = ((const uint2*)src)[i];
  float4 o;
  o.x = b2f(p.x & 0xffffu); o.y = b2f(p.x >> 16);
  o.z = b2f(p.y & 0xffffu); o.w = b2f(p.y >> 16);
  ((float4*)dst)[i] = o;
}

extern "C" void kernel_launch(void* const* d_in, const int* in_sizes, int n_in,
                              void* d_out, int out_size, void* d_ws, size_t ws_size,
                              hipStream_t stream) {
  const float* contents = (const float*)d_in[0];
  const int2*  children = (const int2*)d_in[1];
  const float* W_u = (const float*)d_in[2];
  const float* b_u = (const float*)d_in[3];
  const float* W_h = (const float*)d_in[4];
  const float* b_h = (const float*)d_in[5];
  float* out = (float*)d_out;

  const int B = 64, D = 11, F = 256, H = 512;
  const int N = B * ((1 << D) - 1);            // 131008
  const int NI = B * ((1 << (D - 1)) - 1);     // 65472

  // Workspace (u16 elems): u_bf [N*512] | v_bf [NI*512] | Wub | Whb.
  // emb ping-pong aliases u's internal rows (dead after the v-GEMM).
  u16* ws16 = (u16*)d_ws;
  u16* u_bf = ws16;
  u16* v_bf = ws16 + (size_t)N * H;
  u16* Wub  = v_bf + (size_t)NI * H;
  u16* Whb  = Wub + 512 * 256;
  u16* embA = u_bf;                            // level-9 dst (32768 rows)
  u16* embB = u_bf + (size_t)32768 * 512;

  // --- weight conversion (single tiny launch) ---
  {
    int n = (512 * 256 + 512 * 1536) / 8;
    cvt_weights<<<(n + 255) / 256, 256, 0, stream>>>(W_u, W_h, Wub, Whb);
  }

  // --- GEMM1: u = relu(contents @ W_u^T + b_u) ---
  {
    int mb = (N + 127) / 128;                  // 1024
    gemm1_k64<<<mb * 4, 256, 0, stream>>>(contents, Wub, b_u, u_bf, N, mb);
  }

  // --- v-GEMM: v = u[0:NI] @ W_hu^T (W_h cols 1024..1535 in place) ---
  {
    int mb = (NI + 127) / 128;                 // 512
    gemm_db<2><<<mb * 2, 512, 0, stream>>>(u_bf, nullptr, nullptr,
                                           nullptr, Whb + 1024, 3 * H, nullptr,
                                           v_bf, NI, H, mb);
  }

  // --- tree levels j = D-2 .. 0 (K=1024 children; v in epilogue) ---
  const u16* embPrev = u_bf + (size_t)NI * H;  // leaves = u[NI:]
  u16* dst = embA;
  for (int j = D - 2; j >= 0; --j) {
    int M = B << j;
    int o = B * ((1 << j) - 1);
    int mb = (M + 127) / 128;
    gemm_db<1><<<mb * 2, 512, 0, stream>>>(nullptr, embPrev,
                                           children + o, v_bf + (size_t)o * H,
                                           Whb, 3 * H, b_h, dst, M, 2 * H, mb);
    embPrev = dst;
    dst = (dst == embA) ? embB : embA;
  }

  // --- level-0 emb (64 x 512) -> fp32 output ---
  {
    int n4 = B * H / 4;
    cvt_bf16_to_f32<<<(n4 + 255) / 256, 256, 0, stream>>>(embPrev, out, n4);
  }
}

// Round 9
// 504.249 us; speedup vs baseline: 1.5954x; 1.0876x over previous
//
#include <hip/hip_runtime.h>
#include <hip/hip_bf16.h>

// RecNN: u = relu(contents @ W_u^T + b_u); v = u[internal] @ W_hu^T (hoisted);
// 10 levels emb = relu([emb_L|emb_R] @ W_LR^T + v + b_h).
//
// Round-13:
//  - levels/v-GEMM: exact R10 config (256 thr, 128x128, 3-slot counted
//    vmcnt(4), XOR swizzle, coalesced epilogue) -- part of the 520-us best.
//    R12's 512-thr wide levels regressed (-28 us) and are reverted.
//  - GEMM1: combines the two best measured variants: R6's wide tile
//    (128x256, 512 thr, 16 waves/CU, halved B traffic -> 124.9 us) and
//    R7's 3-slot counted-vmcnt pipeline (114 us on bf16-A). A is fp32
//    reg-staged DEPTH-2: two named register sets (8 f32 each; statically
//    indexed -- rule #20), loaded 2 steps ahead, cvt'd 1 step ahead, so
//    both the A-load->cvt dependency and the B glds are latency-covered.
//    Uniform 4-op vmem groups (2 B glds + 2 A loads), vmcnt(4) per barrier.

typedef unsigned short u16;
typedef __attribute__((ext_vector_type(8))) short bf16x8;
typedef __attribute__((ext_vector_type(4))) float f32x4;
typedef __attribute__((ext_vector_type(2))) float f32x2;

#define BK 32

__device__ __forceinline__ u16 f2b(float f) {
  union { float f; unsigned u; } c; c.f = f;
  unsigned u = c.u;
  return (u16)((u + 0x7fffu + ((u >> 16) & 1u)) >> 16);  // RNE
}

__device__ __forceinline__ float b2f(unsigned hi16) {
  union { float f; unsigned u; } c; c.u = hi16 << 16; return c.f;
}

__device__ __forceinline__ void glds16(const void* g, void* l) {
  __builtin_amdgcn_global_load_lds(
      (__attribute__((address_space(1))) void*)g,
      (__attribute__((address_space(3))) void*)l, 16, 0, 0);
}

// Counted wait + raw barrier. lgkmcnt(0) before the barrier keeps
// stage-after-barrier slot reuse race-free.
template <int N>
__device__ __forceinline__ void wait_barrier() {
  asm volatile("s_waitcnt vmcnt(%0) lgkmcnt(0)" :: "n"(N) : "memory");
  __builtin_amdgcn_s_barrier();
  asm volatile("" ::: "memory");
}

// ---------------------------------------------------------------------------
// GEMM1: u = relu(contents[M][256] @ W_u^T + b_u), out bf16 [M][512].
// 128m x 256n tile, 512 thr (8 waves 2x4, each 64x64), BK=32, nk=8.
// 3-slot LDS rotation; per-iter vmem group = 2 B-glds + 2 A-f32x4 loads;
// vmcnt(4) at each barrier (one group stays in flight across it).
// ---------------------------------------------------------------------------
__global__ __launch_bounds__(512, 2)
void gemm1_wide(const float* __restrict__ A,     // [M][256] fp32
                const u16* __restrict__ W,       // Wub bf16 [512][256]
                const float* __restrict__ bias,
                u16* __restrict__ out,           // [M][512] bf16
                int M, int nBlkM) {
  constexpr int KK = 256, nk = KK / BK;          // 8 steps
  __shared__ __align__(16) char pool[3 * 8192 + 3 * 16384];  // 72 KB
  auto lA = [&](int s) { return (u16*)(pool + s * 8192); };
  auto lB = [&](int s) { return (u16*)(pool + 24576 + s * 16384); };
  float* ep = (float*)pool;   // epilogue alias (33.8 KB, after final sync)

  const int tid  = threadIdx.x;
  const int lane = tid & 63;
  const int wv   = tid >> 6;                 // 0..7
  const int wrow = wv >> 2, wcol = wv & 3;   // 2 x 4 wave grid

  int mb, nb;
  {
    int b = blockIdx.x;
    if ((nBlkM & 7) == 0) {
      int xcd = b & 7;
      nb = (b >> 3) & 1;
      mb = ((b >> 4) << 3) | xcd;
    } else { nb = b & 1; mb = b >> 1; }
  }
  const int mBase = mb * 128;
  const int n0    = nb * 256;

  // A: thread -> row tid>>2 (0..127), logical granule qA = tid&3 (8 f32).
  const int rowA = tid >> 2, qA = tid & 3;
  const int phA  = qA ^ ((tid >> 3) & 3);     // swizzled LDS granule
  const float* a0p;
  { int m0 = min(mBase + rowA, M - 1); a0p = A + (size_t)m0 * KK + qA * 8; }

  // B: 2 glds/thread (rows tid>>2 and +128), preswizzled source granule.
  const int colq = ((tid & 3) ^ ((tid >> 3) & 3)) * 8;
  const u16* bp0 = W + (size_t)(n0 + rowA) * KK + colq;
  const u16* bp1 = W + (size_t)(n0 + rowA + 128) * KK + colq;

  f32x4 acc[4][4] = {};
  const int fm  = lane & 15;
  const int gs8 = ((lane >> 4) ^ ((fm >> 1) & 3)) * 8;   // read-side XOR

  auto stageB = [&](int s, int k0) {
    glds16(bp0 + k0, lB(s) + tid * 8);
    glds16(bp1 + k0, lB(s) + (tid + 512) * 8);
  };
  auto cvtA = [&](int s, float4 (&rg)[2]) {
    union { __hip_bfloat162 h[4]; bf16x8 v; } o;
    o.h[0] = __float22bfloat162_rn({rg[0].x, rg[0].y});
    o.h[1] = __float22bfloat162_rn({rg[0].z, rg[0].w});
    o.h[2] = __float22bfloat162_rn({rg[1].x, rg[1].y});
    o.h[3] = __float22bfloat162_rn({rg[1].z, rg[1].w});
    *(bf16x8*)&lA(s)[(rowA * 4 + phA) * 8] = o.v;
  };
  auto compute = [&](int s) {
    bf16x8 av[4], bv[4];
    const u16* Ab = lA(s);
    const u16* Bb = lB(s);
#pragma unroll
    for (int i = 0; i < 4; i++) {
      av[i] = *(const bf16x8*)&Ab[(wrow * 64 + i * 16 + fm) * BK + gs8];
      bv[i] = *(const bf16x8*)&Bb[(wcol * 64 + i * 16 + fm) * BK + gs8];
    }
    __builtin_amdgcn_s_setprio(1);
#pragma unroll
    for (int i = 0; i < 4; i++)
#pragma unroll
      for (int j = 0; j < 4; j++)
        acc[i][j] = __builtin_amdgcn_mfma_f32_16x16x32_bf16(av[i], bv[j], acc[i][j], 0, 0, 0);
    __builtin_amdgcn_s_setprio(0);
  };

  float4 rgA0[2], rgA1[2];                    // two named reg sets (depth-2 A)

  // --- prologue ---
  { const float4* sp = (const float4*)a0p; rgA0[0] = sp[0]; rgA0[1] = sp[1]; }
  stageB(0, 0);
  cvtA(0, rgA0);                              // compiler waits on rgA0 loads
  asm volatile("" ::: "memory");              // group boundary (B0 = 2 ops)
  stageB(1, BK);
  { const float4* sp = (const float4*)(a0p + BK); rgA1[0] = sp[0]; rgA1[1] = sp[1]; }
  asm volatile("" ::: "memory");              // G_{-1} = 4 ops

  int sl = 0;
  auto iter = [&](int ks, float4 (&ld)[2], float4 (&cv)[2]) {
    wait_barrier<4>();                        // slot ks's B retired; last group in flight
    int s1 = sl + 1; if (s1 == 3) s1 = 0;
    int s2 = s1 + 1; if (s2 == 3) s2 = 0;
    const int k2 = (ks + 2) * BK;
    stageB(s2, k2);                           // B for step ks+2
    { const float4* sp = (const float4*)(a0p + k2); ld[0] = sp[0]; ld[1] = sp[1]; }
    compute(sl);
    cvtA(s1, cv);                             // A(step ks+1), loaded 2 steps ago
    sl = s1;
  };
  // nk-2 = 6 main iters, unrolled x2 so reg-set indices are static.
  for (int ks = 0; ks < nk - 2; ks += 2) {
    iter(ks,     rgA0, rgA1);
    iter(ks + 1, rgA1, rgA0);
  }
  {                                           // ks = nk-2 (even): cv = rgA1
    wait_barrier<4>();
    int s1 = sl + 1; if (s1 == 3) s1 = 0;
    compute(sl);
    cvtA(s1, rgA1);
    sl = s1;
  }
  wait_barrier<0>();                          // drain
  compute(sl);

  __syncthreads();                            // staging dead before ep aliases

  // epilogue: per-wave transpose through LDS, full-line b128 stores
  const int r0  = (lane >> 4) * 4;
  const int err = lane >> 3;
  const int eg  = lane & 7;
  float* epw = ep + wv * 16 * 66;
#pragma unroll
  for (int i = 0; i < 4; i++) {
#pragma unroll
    for (int j = 0; j < 4; j++)
#pragma unroll
      for (int r = 0; r < 4; r++)
        epw[(r0 + r) * 66 + j * 16 + fm] = acc[i][j][r];
    asm volatile("s_waitcnt lgkmcnt(0)" ::: "memory");
    __builtin_amdgcn_sched_barrier(0);
#pragma unroll
    for (int s = 0; s < 2; s++) {
      const int rr  = err + s * 8;
      const int m   = mBase + wrow * 64 + i * 16 + rr;
      const int col = n0 + wcol * 64 + eg * 8;
      float p[8];
#pragma unroll
      for (int h = 0; h < 4; h++) {
        f32x2 t = *(const f32x2*)&epw[rr * 66 + eg * 8 + 2 * h];
        p[2 * h] = t[0]; p[2 * h + 1] = t[1];
      }
      if (m < M) {
        float4 b0v = *(const float4*)(bias + col);
        float4 b1v = *(const float4*)(bias + col + 4);
        float bb[8] = {b0v.x, b0v.y, b0v.z, b0v.w, b1v.x, b1v.y, b1v.z, b1v.w};
        union { u16 u[8]; bf16x8 v; } o;
#pragma unroll
        for (int c = 0; c < 8; c++) {
          float v = p[c] + bb[c];
          o.u[c] = f2b(v > 0.f ? v : 0.f);
        }
        *(bf16x8*)(out + (size_t)m * 512 + col) = o.v;
      }
    }
    __builtin_amdgcn_sched_barrier(0);
  }
}

// ---------------------------------------------------------------------------
// R10 gemm_db (proven in the 520-us best): 128x128 tile, 256 thr, 3-slot
// rotation, counted vmcnt(4), XOR granule swizzle, coalesced epilogue.
// MODE 2: A bf16 [M][K], raw store                               (v-GEMM)
// MODE 1: A gathered [emb[c.x] | emb[c.y]] (K=1024), +v+bias+relu (levels)
// ---------------------------------------------------------------------------
template <int MODE>
__global__ __launch_bounds__(256, 3)
void gemm_db(const u16* __restrict__ Abf,
             const u16* __restrict__ embPrev,
             const int2* __restrict__ idx,
             const u16* __restrict__ vLvl,   // [M][512] bf16
             const u16* __restrict__ W,      // bf16, row stride ldb (B^T)
             int ldb,
             const float* __restrict__ bias,
             u16* __restrict__ out,          // [M][512] bf16
             int M, int K, int nBlkM) {
  __shared__ __align__(16) char pool[6 * 8192];
  auto lAb = [&](int s) { return (u16*)(pool + s * 8192); };
  auto lBp = [&](int s) { return (u16*)(pool + 3 * 8192 + s * 8192); };
  float* ep = (float*)pool;   // epilogue transpose alias (16.9 KB, after sync)

  const int tid  = threadIdx.x;
  const int lane = tid & 63;
  const int wv   = tid >> 6;
  const int wrow = wv >> 1, wcol = wv & 1;

  int mb, nb;
  {
    int b = blockIdx.x;
    if ((nBlkM & 7) == 0) {
      int xcd = b & 7;
      nb = (b >> 3) & 3;
      mb = ((b >> 5) << 3) | xcd;
    } else { nb = b & 3; mb = b >> 2; }
  }
  const int mBase = mb * 128;
  const int n0    = nb * 128;

  const int rowA0 = tid >> 2;
  const int colq  = ((tid & 3) ^ ((tid >> 3) & 3)) * 8;

  const u16 *ab0 = nullptr, *ab1 = nullptr;
  const u16 *aL0 = nullptr, *aR0 = nullptr, *aL1 = nullptr, *aR1 = nullptr;
  {
    int m0 = min(mBase + rowA0, M - 1);
    int m1 = min(mBase + rowA0 + 64, M - 1);
    if (MODE == 2) {
      ab0 = Abf + (size_t)m0 * K + colq;
      ab1 = Abf + (size_t)m1 * K + colq;
    } else {
      int2 c0 = idx[m0], c1 = idx[m1];
      aL0 = embPrev + (size_t)c0.x * 512 + colq;
      aR0 = embPrev + (size_t)c0.y * 512 + colq;
      aL1 = embPrev + (size_t)c1.x * 512 + colq;
      aR1 = embPrev + (size_t)c1.y * 512 + colq;
    }
  }
  const u16* bp0 = W + (size_t)(n0 + rowA0) * ldb + colq;
  const u16* bp1 = W + (size_t)(n0 + rowA0 + 64) * ldb + colq;

  f32x4 acc[4][4] = {};
  const int fm  = lane & 15;
  const int q   = lane >> 4;
  const int gs8 = (q ^ ((fm >> 1) & 3)) * 8;
  const int nk  = K / BK;

  auto stage = [&](int s, int k0) {
    if (MODE == 2) {
      glds16(ab0 + k0, lAb(s) + tid * 8);
      glds16(ab1 + k0, lAb(s) + (tid + 256) * 8);
    } else {  // gather; colq < 32 elems never flips the L/R bit
      const u16* g0 = ((k0 & 512) ? aR0 : aL0) + (k0 & 511);
      const u16* g1 = ((k0 & 512) ? aR1 : aL1) + (k0 & 511);
      glds16(g0, lAb(s) + tid * 8);
      glds16(g1, lAb(s) + (tid + 256) * 8);
    }
    glds16(bp0 + k0, lBp(s) + tid * 8);
    glds16(bp1 + k0, lBp(s) + (tid + 256) * 8);
  };

  auto compute = [&](int s) {
    bf16x8 av[4], bv[4];
    const u16* Ab = lAb(s);
    const u16* Bb = lBp(s);
#pragma unroll
    for (int i = 0; i < 4; i++) {
      av[i] = *(const bf16x8*)&Ab[(wrow * 64 + i * 16 + fm) * BK + gs8];
      bv[i] = *(const bf16x8*)&Bb[(wcol * 64 + i * 16 + fm) * BK + gs8];
    }
    __builtin_amdgcn_s_setprio(1);
#pragma unroll
    for (int i = 0; i < 4; i++)
#pragma unroll
      for (int j = 0; j < 4; j++)
        acc[i][j] = __builtin_amdgcn_mfma_f32_16x16x32_bf16(av[i], bv[j], acc[i][j], 0, 0, 0);
    __builtin_amdgcn_s_setprio(0);
  };

  stage(0, 0);
  asm volatile("" ::: "memory");
  stage(1, BK);

  int sl = 0;
  for (int ks = 0; ks < nk - 2; ks++) {
    wait_barrier<4>();
    int s1 = sl + 1; if (s1 == 3) s1 = 0;
    int s2 = s1 + 1; if (s2 == 3) s2 = 0;
    stage(s2, (ks + 2) * BK);
    compute(sl);
    sl = s1;
  }
  {
    wait_barrier<4>();
    int s1 = sl + 1; if (s1 == 3) s1 = 0;
    compute(sl);
    sl = s1;
  }
  wait_barrier<0>();
  compute(sl);

  __syncthreads();

  const int r0  = (lane >> 4) * 4;
  const int err = lane >> 3;
  const int eg  = lane & 7;
  float* epw = ep + wv * 16 * 66;
#pragma unroll
  for (int i = 0; i < 4; i++) {
#pragma unroll
    for (int j = 0; j < 4; j++)
#pragma unroll
      for (int r = 0; r < 4; r++)
        epw[(r0 + r) * 66 + j * 16 + fm] = acc[i][j][r];
    asm volatile("s_waitcnt lgkmcnt(0)" ::: "memory");
    __builtin_amdgcn_sched_barrier(0);
#pragma unroll
    for (int s = 0; s < 2; s++) {
      const int rr  = err + s * 8;
      const int m   = mBase + wrow * 64 + i * 16 + rr;
      const int col = n0 + wcol * 64 + eg * 8;
      float p[8];
#pragma unroll
      for (int h = 0; h < 4; h++) {
        f32x2 t = *(const f32x2*)&epw[rr * 66 + eg * 8 + 2 * h];
        p[2 * h] = t[0]; p[2 * h + 1] = t[1];
      }
      if (m < M) {
        float bb[8];
        if (MODE != 2) {
          float4 b0v = *(const float4*)(bias + col);
          float4 b1v = *(const float4*)(bias + col + 4);
          bb[0] = b0v.x; bb[1] = b0v.y; bb[2] = b0v.z; bb[3] = b0v.w;
          bb[4] = b1v.x; bb[5] = b1v.y; bb[6] = b1v.z; bb[7] = b1v.w;
        }
        union { u16 u[8]; bf16x8 v; } vl;
        if (MODE == 1) vl.v = *(const bf16x8*)(vLvl + (size_t)m * 512 + col);
        union { u16 u[8]; bf16x8 v; } o;
#pragma unroll
        for (int c = 0; c < 8; c++) {
          float v = p[c];
          if (MODE != 2) v += bb[c];
          if (MODE == 1) v += b2f(vl.u[c]);
          if (MODE != 2) v = v > 0.f ? v : 0.f;
          o.u[c] = f2b(v);
        }
        *(bf16x8*)(out + (size_t)m * 512 + col) = o.v;
      }
    }
    __builtin_amdgcn_sched_barrier(0);
  }
}

// One launch: convert W_u (512x256) and W_h (512x1536) fp32 -> bf16.
__global__ void cvt_weights(const float* __restrict__ Wu,
                            const float* __restrict__ Wh,
                            u16* __restrict__ Wub, u16* __restrict__ Whb) {
  const int nWu = 512 * 256 / 8;
  const int nWh = 512 * 1536 / 8;
  int i = blockIdx.x * blockDim.x + threadIdx.x;
  const float* src; u16* dst; int c;
  if (i < nWu) { src = Wu; dst = Wub; c = i; }
  else if (i < nWu + nWh) { src = Wh; dst = Whb; c = i - nWu; }
  else return;
  const float4* s = (const float4*)(src + (size_t)c * 8);
  float4 a = s[0], b = s[1];
  union { u16 u[8]; bf16x8 v; } o;
  o.u[0] = f2b(a.x); o.u[1] = f2b(a.y); o.u[2] = f2b(a.z); o.u[3] = f2b(a.w);
  o.u[4] = f2b(b.x); o.u[5] = f2b(b.y); o.u[6] = f2b(b.z); o.u[7] = f2b(b.w);
  *(bf16x8*)(dst + (size_t)c * 8) = o.v;
}

__global__ void cvt_bf16_to_f32(const u16* __restrict__ src, float* __restrict__ dst, int n4) {
  int i = blockIdx.x * blockDim.x + threadIdx.x;
  if (i >= n4) return;
  uint2 p = ((const uint2*)src)[i];
  float4 o;
  o.x = b2f(p.x & 0xffffu); o.y = b2f(p.x >> 16);
  o.z = b2f(p.y & 0xffffu); o.w = b2f(p.y >> 16);
  ((float4*)dst)[i] = o;
}

extern "C" void kernel_launch(void* const* d_in, const int* in_sizes, int n_in,
                              void* d_out, int out_size, void* d_ws, size_t ws_size,
                              hipStream_t stream) {
  const float* contents = (const float*)d_in[0];
  const int2*  children = (const int2*)d_in[1];
  const float* W_u = (const float*)d_in[2];
  const float* b_u = (const float*)d_in[3];
  const float* W_h = (const float*)d_in[4];
  const float* b_h = (const float*)d_in[5];
  float* out = (float*)d_out;

  const int B = 64, D = 11, F = 256, H = 512;
  const int N = B * ((1 << D) - 1);            // 131008
  const int NI = B * ((1 << (D - 1)) - 1);     // 65472

  // Workspace (u16 elems): u_bf [N*512] | v_bf [NI*512] | Wub | Whb.
  // emb ping-pong aliases u's internal rows (dead after the v-GEMM).
  u16* ws16 = (u16*)d_ws;
  u16* u_bf = ws16;
  u16* v_bf = ws16 + (size_t)N * H;
  u16* Wub  = v_bf + (size_t)NI * H;
  u16* Whb  = Wub + 512 * 256;
  u16* embA = u_bf;                            // level-9 dst (32768 rows)
  u16* embB = u_bf + (size_t)32768 * 512;

  // --- weight conversion (single tiny launch) ---
  {
    int n = (512 * 256 + 512 * 1536) / 8;
    cvt_weights<<<(n + 255) / 256, 256, 0, stream>>>(W_u, W_h, Wub, Whb);
  }

  // --- GEMM1: u = relu(contents @ W_u^T + b_u) ---
  {
    int mb = (N + 127) / 128;                  // 1024
    gemm1_wide<<<mb * 2, 512, 0, stream>>>(contents, Wub, b_u, u_bf, N, mb);
  }

  // --- v-GEMM: v = u[0:NI] @ W_hu^T (W_h cols 1024..1535 in place) ---
  {
    int mb = (NI + 127) / 128;                 // 512
    gemm_db<2><<<mb * 4, 256, 0, stream>>>(u_bf, nullptr, nullptr,
                                           nullptr, Whb + 1024, 3 * H, nullptr,
                                           v_bf, NI, H, mb);
  }

  // --- tree levels j = D-2 .. 0 (K=1024 children; v in epilogue) ---
  const u16* embPrev = u_bf + (size_t)NI * H;  // leaves = u[NI:]
  u16* dst = embA;
  for (int j = D - 2; j >= 0; --j) {
    int M = B << j;
    int o = B * ((1 << j) - 1);
    int mb = (M + 127) / 128;
    gemm_db<1><<<mb * 4, 256, 0, stream>>>(nullptr, embPrev,
                                           children + o, v_bf + (size_t)o * H,
                                           Whb, 3 * H, b_h, dst, M, 2 * H, mb);
    embPrev = dst;
    dst = (dst == embA) ? embB : embA;
  }

  // --- level-0 emb (64 x 512) -> fp32 output ---
  {
    int n4 = B * H / 4;
    cvt_bf16_to_f32<<<(n4 + 255) / 256, 256, 0, stream>>>(embPrev, out, n4);
  }
}